// Round 8
// baseline (96.889 us; speedup 1.0000x reference)
//
#include <hip/hip_runtime.h>

#define HW_     12544   // 112*112
#define W_      112
#define NP_     4096    // planes = 32*128
#define OHW_    3136
#define OW_     56
#define HPLANE  (112*56)
#define NSTRIDE 8       // u64 stride per norm counter (64 B padding, own cacheline)

__device__ __forceinline__ unsigned bf16rn(float a) {
    unsigned u = __float_as_uint(a);
    return (u + 0x7FFFu + ((u >> 16) & 1u)) >> 16;
}
__device__ __forceinline__ unsigned pack2(float lo, float hi) {
    return bf16rn(lo) | (bf16rn(hi) << 16);
}

// ---------------- Pass 1: streaming h-blur (both dc, bf16) + fixed-point norm atomics ----
// grid 12544 x 256. task g = (plane bc, row r, 16-col seg s). 6 contiguous float4
// loads, static-index h extraction, 2x uint4 stores. 392 blocks per batch (exact).
__global__ __launch_bounds__(256) void hsum(const float* __restrict__ inp,
                                            ushort* __restrict__ hb,
                                            unsigned long long* __restrict__ nsum) {
    const int g   = blockIdx.x * 256 + threadIdx.x;   // exactly 4096*784
    const int bc  = g / 784;
    const int rem = g - bc * 784;
    const int r   = rem / 7;
    const int s   = rem - r * 7;

    const int base4 = (s == 0) ? 0 : ((s == 6) ? 22 : 4 * s - 1);
    const float4* rp = (const float4*)(inp + (size_t)bc * HW_ + r * W_) + base4;
    const float4 v0 = rp[0], v1 = rp[1], v2 = rp[2];
    const float4 v3 = rp[3], v4 = rp[4], v5 = rp[5];
    const float x[24] = {v0.x,v0.y,v0.z,v0.w, v1.x,v1.y,v1.z,v1.w,
                         v2.x,v2.y,v2.z,v2.w, v3.x,v3.y,v3.z,v3.w,
                         v4.x,v4.y,v4.z,v4.w, v5.x,v5.y,v5.z,v5.w};

    float h0[8], h1[8], se = 0.f, so = 0.f;
    if (s == 0) {                                   // x = cols 0..23, owns 0..15
#pragma unroll
        for (int m = 0; m < 16; m += 2) { se += x[m]*x[m]; so += x[m+1]*x[m+1]; }
        h0[0] = 3.f*x[0] + 4.f*x[1] + x[2];         // reflect col -1 -> 1
#pragma unroll
        for (int u = 1; u < 8; ++u)
            h0[u] = (x[2*u-1] + x[2*u+2]) + 3.f*(x[2*u] + x[2*u+1]);
#pragma unroll
        for (int u = 0; u < 8; ++u)
            h1[u] = (x[2*u] + x[2*u+3]) + 3.f*(x[2*u+1] + x[2*u+2]);
    } else if (s == 6) {                            // x = cols 88..111, owns 96..111
#pragma unroll
        for (int m = 8; m < 24; m += 2) { se += x[m]*x[m]; so += x[m+1]*x[m+1]; }
#pragma unroll
        for (int u = 0; u < 7; ++u)
            h0[u] = (x[7+2*u] + x[10+2*u]) + 3.f*(x[8+2*u] + x[9+2*u]);
        h0[7] = x[21] + 4.f*x[22] + 3.f*x[23];      // reflect cols 112/113
#pragma unroll
        for (int u = 0; u < 7; ++u)
            h1[u] = (x[8+2*u] + x[11+2*u]) + 3.f*(x[9+2*u] + x[10+2*u]);
        h1[7] = h0[7];
    } else {                                        // x = cols 16s-4..16s+19, owns 16s..16s+15
#pragma unroll
        for (int m = 0; m < 16; m += 2) { se += x[m+4]*x[m+4]; so += x[m+5]*x[m+5]; }
#pragma unroll
        for (int u = 0; u < 8; ++u) {
            h0[u] = (x[2*u+3] + x[2*u+6]) + 3.f*(x[2*u+4] + x[2*u+5]);
            h1[u] = (x[2*u+4] + x[2*u+7]) + 3.f*(x[2*u+5] + x[2*u+6]);
        }
    }

    const uint4 o0 = make_uint4(pack2(h0[0],h0[1]), pack2(h0[2],h0[3]),
                                pack2(h0[4],h0[5]), pack2(h0[6],h0[7]));
    const uint4 o1 = make_uint4(pack2(h1[0],h1[1]), pack2(h1[2],h1[3]),
                                pack2(h1[4],h1[5]), pack2(h1[6],h1[7]));
    *(uint4*)(hb + (size_t)bc * HPLANE + r * 56 + 8 * s) = o0;
    *(uint4*)(hb + (size_t)(NP_ + bc) * HPLANE + r * 56 + 8 * s) = o1;

    // phase partials: phase = (r&1) + 2*(col&1)
    const int rpar = r & 1;
    float s0 = rpar ? 0.f : se, s1 = rpar ? se : 0.f;
    float s2 = rpar ? 0.f : so, s3 = rpar ? so : 0.f;
    for (int off = 32; off > 0; off >>= 1) {
        s0 += __shfl_down(s0, off); s1 += __shfl_down(s1, off);
        s2 += __shfl_down(s2, off); s3 += __shfl_down(s3, off);
    }
    __shared__ float ws4[4][4];
    const int tid = threadIdx.x;
    if ((tid & 63) == 0) {
        const int w = tid >> 6;
        ws4[w][0] = s0; ws4[w][1] = s1; ws4[w][2] = s2; ws4[w][3] = s3;
    }
    __syncthreads();
    if (tid < 4) {
        const float v = ws4[0][tid] + ws4[1][tid] + ws4[2][tid] + ws4[3][tid];
        const int b = blockIdx.x / 392;             // batch (12544 = 32*392)
        // deterministic: per-block float partial -> 2^20 fixed-point u64, integer
        // atomics commute exactly across replays. Quantum ~1e-3 << phase gaps ~1e3.
        atomicAdd(&nsum[(b * 4 + tid) * NSTRIDE],
                  (unsigned long long)((double)v * 1048576.0));
    }
}

// ---------------- Pass 2: per-block integer argmax + v-blur of selected-dc bf16 h ----
__global__ __launch_bounds__(256) void vblur(const ushort* __restrict__ hb,
                                             const unsigned long long* __restrict__ nsum,
                                             float* __restrict__ out) {
    __shared__ int pidx[32];
    const int tid = threadIdx.x;
    if (tid < 32) {
        const unsigned long long* q = nsum + (size_t)tid * 4 * NSTRIDE;
        const unsigned long long a = q[0], b = q[NSTRIDE], c = q[2*NSTRIDE], d = q[3*NSTRIDE];
        int ix = 0; unsigned long long best = a;
        if (b > best) { best = b; ix = 1; }
        if (c > best) { best = c; ix = 2; }
        if (d > best) { best = d; ix = 3; }
        pidx[tid] = ix;
    }
    __syncthreads();

    const int g  = blockIdx.x * 256 + tid;           // exactly 4096*392
    const int bc = g / 392;
    const int rr = g - bc * 392;
    const int oh = rr / 7;
    const int s  = rr - oh * 7;
    const int ph = pidx[bc >> 7];
    const int dr = ph & 1, dc = ph >> 1;
    const uint4* H = (const uint4*)(hb + ((size_t)(dc ? NP_ + bc : bc)) * HPLANE);
    const int jb = 2 * oh + dr - 1;

    uint4 w[4];
#pragma unroll
    for (int k = 0; k < 4; ++k) {
        int j = jb + k;
        int aj = j < 0 ? -j : j;
        j = aj < 222 - aj ? aj : 222 - aj;
        w[k] = H[j * 7 + s];
    }

    float acc[8];
#pragma unroll
    for (int k = 0; k < 4; ++k) {
        const unsigned a = w[k].x, b = w[k].y, c = w[k].z, d = w[k].w;
        float y[8];
        y[0] = __uint_as_float(a << 16); y[1] = __uint_as_float(a & 0xFFFF0000u);
        y[2] = __uint_as_float(b << 16); y[3] = __uint_as_float(b & 0xFFFF0000u);
        y[4] = __uint_as_float(c << 16); y[5] = __uint_as_float(c & 0xFFFF0000u);
        y[6] = __uint_as_float(d << 16); y[7] = __uint_as_float(d & 0xFFFF0000u);
        const float wk = (k == 1 || k == 2) ? 3.f : 1.f;
        if (k == 0) {
#pragma unroll
            for (int u = 0; u < 8; ++u) acc[u] = y[u];
        } else {
#pragma unroll
            for (int u = 0; u < 8; ++u) acc[u] = fmaf(wk, y[u], acc[u]);
        }
    }

    float* o = out + (size_t)bc * OHW_ + oh * OW_ + 8 * s;
    *(float4*)o = make_float4(acc[0] * 0.015625f, acc[1] * 0.015625f,
                              acc[2] * 0.015625f, acc[3] * 0.015625f);
    *(float4*)(o + 4) = make_float4(acc[4] * 0.015625f, acc[5] * 0.015625f,
                                    acc[6] * 0.015625f, acc[7] * 0.015625f);
}

extern "C" void kernel_launch(void* const* d_in, const int* in_sizes, int n_in,
                              void* d_out, int out_size, void* d_ws, size_t ws_size,
                              hipStream_t stream) {
    const float* inp = (const float*)d_in[0];
    ushort* hb = (ushort*)d_ws;                             // 2*4096*112*56*2 = 102,760,448 B
    unsigned long long* nsum =
        (unsigned long long*)((char*)d_ws + 102760448);     // 128 counters * 64 B = 8192 B
    hipMemsetAsync(nsum, 0, 32 * 4 * NSTRIDE * sizeof(unsigned long long), stream);
    hsum<<<12544, 256, 0, stream>>>(inp, hb, nsum);
    vblur<<<6272, 256, 0, stream>>>(hb, nsum, (float*)d_out);
}